// Round 2
// 61.869 us; speedup vs baseline: 1.0876x; 1.0876x over previous
//
#include <hip/hip_runtime.h>
#include <math.h>

static constexpr int B   = 512;
static constexpr int NP  = 128;
static constexpr int NG  = 128;
static constexpr int TT  = 5;
static constexpr float INV_CNT = 1.0f / (float)(B * NP * 2);

// One block per batch, 512 threads = (h in 0..3, p in 0..127): 4 threads per
// pred point, each owning 32 of the 128 gt edges.
//
// Instead of evaluating all TT=5 interpolated samples per edge, note that
// dist^2(p, r + s*e) is a CONVEX quadratic in s, so the argmin over the 5
// evenly spaced samples on edge i is the sample nearest the parabola vertex
//   t* = e2.(p-r)/|e2|^2   (e2 = 0.2*(v-r), sample n at r + n*e2, n in 0..4)
//   n  = clamp(rint(t*), 0, 4)
// One analytic eval (~13 VALU, 1.25 LDS b128) replaces 5 distance evals
// (~30 VALU, 2.5 LDS b128) per edge. Packed-u32 argmin key as before:
// (bits(d) & ~1023) | (i*5+n); d >= 0 so float order == uint order; ties
// resolve to smallest index.
__global__ __launch_bounds__(512) void dm_main(
    const float* __restrict__ pred,   // [B, NP, 2]
    const float* __restrict__ gt,     // [B, NG, 2]
    float* __restrict__ partial)      // [B]
{
    __shared__ float4   sA[NG];       // per edge: {r.x, r.y, e2.x, e2.y}
    __shared__ float    sQ[NG];       // per edge: 1/|e2|^2
    __shared__ float    sgt[NG * 2];
    __shared__ unsigned skey[512];
    __shared__ float    swsum[2];

    const int b   = blockIdx.x;
    const int tid = threadIdx.x;

    // stage gt polygon (1 KB), float4-coalesced
    const float* gtb = gt + (size_t)b * NG * 2;
    if (tid < 64) ((float4*)sgt)[tid] = ((const float4*)gtb)[tid];
    __syncthreads();

    // per-edge precompute: r = gt[i-1 mod NG], e2 = 0.2*(gt[i]-r), q = 1/|e2|^2
    if (tid < NG) {
        const int i  = tid;
        const int ip = (i == 0) ? (NG - 1) : (i - 1);
        const float rx = sgt[2*ip], ry = sgt[2*ip+1];
        const float ex = 0.2f * (sgt[2*i]   - rx);
        const float ey = 0.2f * (sgt[2*i+1] - ry);
        sA[i] = make_float4(rx, ry, ex, ey);
        sQ[i] = 1.0f / fmaf(ex, ex, ey * ey);
    }
    __syncthreads();

    const int p = tid & (NP - 1);
    const int h = tid >> 7;                       // 0..3 -> edges [h*32, h*32+32)
    const float2 pv = ((const float2*)(pred + (size_t)b * NP * 2))[p];
    const float px = pv.x, py = pv.y;

    unsigned kmin = 0xFFFFFFFFu;
    const int e0 = h * 32;
    const float4* sQ4 = (const float4*)sQ;
    #pragma unroll
    for (int jj = 0; jj < 8; ++jj) {              // 8 groups of 4 edges
        const float4 qv = sQ4[h * 8 + jj];        // wave-uniform broadcast
        #pragma unroll
        for (int k = 0; k < 4; ++k) {
            const int i = e0 + jj * 4 + k;
            const float4 A = sA[i];               // wave-uniform broadcast
            const float wx = px - A.x, wy = py - A.y;
            const float dot = fmaf(wx, A.z, wy * A.w);
            const float q = (k == 0) ? qv.x : (k == 1) ? qv.y : (k == 2) ? qv.z : qv.w;
            float n = rintf(dot * q);             // vertex in sample units (v_rndne)
            n = fminf(fmaxf(n, 0.0f), 4.0f);      // clamp; NaN (degenerate edge) -> 0
            const float ux = fmaf(-n, A.z, wx);   // p - (r + n*e2)
            const float uy = fmaf(-n, A.w, wy);
            const float d  = fmaf(ux, ux, uy * uy);
            const unsigned idx = (unsigned)(i * 5) + (unsigned)n;
            kmin = min(kmin, (__float_as_uint(d) & 0xFFFFFC00u) | idx);
        }
    }
    skey[tid] = kmin;
    __syncthreads();

    if (tid < 128) {                              // waves 0,1 fully active
        const unsigned k = min(min(skey[tid],       skey[tid + 128]),
                               min(skey[tid + 256], skey[tid + 384]));
        const unsigned idx = k & 1023u;
        const unsigned i   = (idx * 205u) >> 10;  // exact /5 for idx < 948
        const float    n   = (float)(idx - 5u * i);
        const float4 A = sA[i];
        const float mx = fmaf(n, A.z, A.x);       // matched point r + n*e2
        const float my = fmaf(n, A.w, A.y);
        const float dx = fabsf(px - mx);
        const float dy = fabsf(py - my);
        const float lx = (dx < 1.0f) ? 0.5f * dx * dx : dx - 0.5f;
        const float ly = (dy < 1.0f) ? 0.5f * dy * dy : dy - 0.5f;
        float v = lx + ly;
        #pragma unroll
        for (int off = 32; off > 0; off >>= 1) v += __shfl_down(v, off);
        if ((tid & 63) == 0) swsum[tid >> 6] = v;
    }
    __syncthreads();
    if (tid == 0) partial[b] = swsum[0] + swsum[1];
}

__global__ __launch_bounds__(256) void dm_finalize(
    const float* __restrict__ partial, float* __restrict__ out)
{
    __shared__ float s[4];
    const int tid = threadIdx.x;
    float v = partial[tid] + partial[tid + 256];
    #pragma unroll
    for (int off = 32; off > 0; off >>= 1) v += __shfl_down(v, off);
    if ((tid & 63) == 0) s[tid >> 6] = v;
    __syncthreads();
    if (tid == 0) out[0] = (s[0] + s[1] + s[2] + s[3]) * INV_CNT;
}

extern "C" void kernel_launch(void* const* d_in, const int* in_sizes, int n_in,
                              void* d_out, int out_size, void* d_ws, size_t ws_size,
                              hipStream_t stream) {
    // inputs: [0] init_polys (unused), [1] pred_poly [512,128,2] f32,
    //         [2] gt_polys [512,128,2] f32
    const float* pred = (const float*)d_in[1];
    const float* gt   = (const float*)d_in[2];
    float* partial    = (float*)d_ws;   // 512 * 4 B scratch

    dm_main<<<B, 512, 0, stream>>>(pred, gt, partial);
    dm_finalize<<<1, 256, 0, stream>>>(partial, (float*)d_out);
}